// Round 7
// baseline (144.448 us; speedup 1.0000x reference)
//
#include <hip/hip_runtime.h>
#include <hip/hip_bf16.h>

namespace {

constexpr int HEADS = 4;
constexpr int DQ    = 128;
constexpr int KVB   = 32;
constexpr int QB    = 128;
constexpr int NQT   = 3;               // max len 383 -> 3 q-tiles of 128
constexpr int ROWF  = 3 * DQ * HEADS;  // 1536 floats per token row
constexpr float ALPHA = 0.08838834764831843f;
constexpr float INV_N = 1.0f / 512.0f;

typedef __bf16 bf16x8 __attribute__((ext_vector_type(8)));
typedef float  f32x16 __attribute__((ext_vector_type(16)));
typedef float  f32x4  __attribute__((ext_vector_type(4)));
typedef unsigned int u32;
typedef u32 u32x4 __attribute__((ext_vector_type(4)));

union FragU { u32x4 u; bf16x8 v; };

__device__ __forceinline__ u32 pkbf(float lo, float hi) {
  u32 r;
  asm("v_cvt_pk_bf16_f32 %0, %1, %2" : "=v"(r) : "v"(lo), "v"(hi));
  return r;
}

__device__ __forceinline__ u32 xor32(u32 x) {
  return (u32)__shfl_xor((int)x, 32, 64);
}

__device__ __forceinline__ float silu_p(float acc) {
  float s = acc * ALPHA;
  return s * INV_N * __builtin_amdgcn_rcpf(1.0f + __expf(-s));
}

#define GLOAD16(gp, lp) \
  __builtin_amdgcn_global_load_lds((const __attribute__((address_space(1))) u32*)(gp), \
                                   (__attribute__((address_space(3))) u32*)(lp), 16, 0, 0)

} // namespace

// Block = (qt, b, h): 4 waves, wave w owns q-rows qt*128 + 32w .. +31.
// KVB=32: Kf dbuf 2x16KB + Vtb 8KB = 40KB LDS -> 3 blocks/CU (12 waves/CU).
// K: f32 double-buffered LDS via global_load_lds (read-time cvt to bf16).
// V: reg-staged (pinned, 4 VGPRs) -> packed bf16 V^T single-buffered LDS.
__global__ __launch_bounds__(256, 3)
void hstu_attn_kernel(const float* __restrict__ qkv,
                      const int* __restrict__ seq_offsets,
                      float* __restrict__ out,
                      int Z)
{
  const int xi = blockIdx.x;
  const int qt = (NQT - 1) - xi / Z;          // heavy q-tiles first
  const int b  = (Z - 1) - (xi % Z);          // long sequences first
  const int h  = blockIdx.y;
  const int off = seq_offsets[b];
  const int len = seq_offsets[b + 1] - off;
  if (qt * QB >= len) return;

  __shared__ __align__(16) float          Kf[2][KVB * DQ];  // 2 x 16 KB f32
  __shared__ __align__(16) unsigned short Vtb[KVB * DQ];    // 8 KB bf16 V^T

  const int t   = threadIdx.x;
  const int w   = t >> 6;
  const int l   = t & 63;
  const int l31 = l & 31;
  const int gg  = l >> 5;
  const int nb  = qt * QB + 32 * w;   // wave's first q row

  const float* __restrict__ base = qkv + (size_t)off * ROWF + h * (3 * DQ);

  // ---- K staging: 16 gload calls (4/wave, waves 0-3), rows 2i,2i+1 per call ----
  const int khalf = l >> 5;          // row within pair
  const int kslot = (l & 31) >> 1;   // physical 32B slot 0..15
  const int khb   = l & 1;           // 16B half within slot

  auto issue_k = [&](int m0, int buf) {
    if (w < 4) {
#pragma unroll
      for (int jj = 0; jj < 4; jj++) {
        int i  = w * 4 + jj;
        int r  = 2 * i + khalf;
        int rm = m0 + r; rm = rm < len ? rm : len - 1;
        int Ls = kslot ^ (i & 15);               // logical 32B slot (involution)
        GLOAD16(base + (size_t)rm * ROWF + DQ + Ls * 8 + khb * 4,
                (char*)Kf[buf] + i * 1024);
      }
    }
  };

  // ---- V staging: thread owns rows (m0p, m0p+1), d-range d0v..d0v+7 ----
  const int m0p = (t >> 4) * 2;
  const int d0v = (t & 15) * 8;
  f32x4 vraw[4];

  auto issue_v = [&](int m0) {
    int r0 = m0 + m0p;     r0 = r0 < len ? r0 : len - 1;
    int r1 = m0 + m0p + 1; r1 = r1 < len ? r1 : len - 1;
    const f32x4* p0 = (const f32x4*)(base + (size_t)r0 * ROWF + 2 * DQ + d0v);
    const f32x4* p1 = (const f32x4*)(base + (size_t)r1 * ROWF + 2 * DQ + d0v);
    vraw[0] = p0[0]; vraw[1] = p0[1];
    vraw[2] = p1[0]; vraw[3] = p1[1];
#pragma unroll
    for (int i = 0; i < 4; i++) asm volatile("" :: "v"(vraw[i]));  // pin: no sinking
  };

  auto pack_v = [&]() {
#pragma unroll
    for (int jj = 0; jj < 8; jj++) {
      int d   = d0v + jj;
      int row = d >> 1;
      int ch  = (d & 1) * 4 + (m0p >> 3);
      u32 pv  = pkbf(vraw[jj >> 2][jj & 3], vraw[2 + (jj >> 2)][jj & 3]);
      *(u32*)((char*)Vtb + row * 128 + ((ch ^ (row & 7)) << 4) + (m0p & 7) * 2) = pv;
    }
  };

  issue_k(0, 0);
  issue_v(0);

  // ---- Q fragments (B-operand of swapped QK^T): lane holds Q[n=l31][d=16ks+8gg+j] ----
  bf16x8 qf[8];
  {
    int n  = nb + l31;
    int rq = n < len ? n : len - 1;   // clamped rows never stored
    const float* qrow = base + (size_t)rq * ROWF;
#pragma unroll
    for (int ks = 0; ks < 8; ks++) {
      int d = ks * 16 + gg * 8;
      f32x4 a0 = *(const f32x4*)(qrow + d);
      f32x4 a1 = *(const f32x4*)(qrow + d + 4);
      FragU u;
      u.u[0] = pkbf(a0[0], a0[1]);
      u.u[1] = pkbf(a0[2], a0[3]);
      u.u[2] = pkbf(a1[0], a1[1]);
      u.u[3] = pkbf(a1[2], a1[3]);
      qf[ks] = u.v;
    }
  }

  f32x16 Of[4];
#pragma unroll
  for (int i = 0; i < 4; i++)
#pragma unroll
    for (int r = 0; r < 16; r++) Of[i][r] = 0.0f;

  const int nkv = min((len + KVB - 1) >> 5, 4 * qt + 4);
  int cur = 0;

  for (int kvt = 0; kvt < nkv; kvt++) {
    const int m0 = kvt * KVB;

    pack_v();   // compiler vmcnt wait for vraw drains (older) K gloads too
    if (kvt + 1 < nkv) {
      issue_k(m0 + KVB, cur ^ 1);   // stays in flight across the barrier
      issue_v(m0 + KVB);
    }
    asm volatile("s_waitcnt lgkmcnt(0)" ::: "memory");
    __builtin_amdgcn_s_barrier();
    __builtin_amdgcn_sched_barrier(0);

    if (nb < len && m0 <= nb + 31) {   // wave-uniform causal skip
      const bool needmask = (m0 + KVB - 1) > nb;

      // ---- QK^T: S^T tile 32m x 32n ----
      f32x16 acc;
#pragma unroll
      for (int r = 0; r < 16; r++) acc[r] = 0.0f;
      const int mrow = l31;
      const char* krow = (const char*)Kf[cur] + mrow * 512;
      const int   ksw  = (mrow >> 1) & 15;
      __builtin_amdgcn_s_setprio(1);
#pragma unroll
      for (int ks = 0; ks < 8; ks++) {
        int J = 2 * ks + gg;
        const f32x4* kp = (const f32x4*)(krow + ((J ^ ksw) << 5));
        f32x4 k0 = kp[0], k1 = kp[1];
        FragU u;
        u.u[0] = pkbf(k0[0], k0[1]);
        u.u[1] = pkbf(k0[2], k0[3]);
        u.u[2] = pkbf(k1[0], k1[1]);
        u.u[3] = pkbf(k1[2], k1[3]);
        // S^T = K * Q^T : lane holds n=l31, m=(r&3)+8(r>>2)+4gg
        acc = __builtin_amdgcn_mfma_f32_32x32x16_bf16(u.v, qf[ks], acc, 0, 0, 0);
      }
      __builtin_amdgcn_s_setprio(0);

      // silu + causal mask, pack bf16 pairs (m, m+1)
      u32 wk[8];
#pragma unroll
      for (int i = 0; i < 8; i++) {
        int r  = 2 * i;
        int mr = m0 + (r & 3) + 8 * (r >> 2) + 4 * gg;
        float p0 = silu_p(acc[r]);
        float p1 = silu_p(acc[r + 1]);
        if (needmask) {
          int nglob = nb + l31;
          if (mr > nglob)     p0 = 0.0f;
          if (mr + 1 > nglob) p1 = 0.0f;
        }
        wk[i] = pkbf(p0, p1);
      }

      // redistribute halves lane<->lane+32 -> PV A-frags (k = 8gg + j)
      bf16x8 pa[2];
      {
        FragU fa, fb;
        u32 t0 = xor32(wk[0]); u32 t2 = xor32(wk[2]);
        fa.u[0] = gg ? t2 : wk[0]; fa.u[2] = gg ? wk[2] : t0;
        u32 t1 = xor32(wk[1]); u32 t3 = xor32(wk[3]);
        fa.u[1] = gg ? t3 : wk[1]; fa.u[3] = gg ? wk[3] : t1;
        u32 t4 = xor32(wk[4]); u32 t6 = xor32(wk[6]);
        fb.u[0] = gg ? t6 : wk[4]; fb.u[2] = gg ? wk[6] : t4;
        u32 t5 = xor32(wk[5]); u32 t7 = xor32(wk[7]);
        fb.u[1] = gg ? t7 : wk[5]; fb.u[3] = gg ? wk[7] : t5;
        pa[0] = fa.v;
        pa[1] = fb.v;
      }

      // ---- PV: O += P * V^T (A = P frags in reg, B = V^T from LDS) ----
      __builtin_amdgcn_s_setprio(1);
#pragma unroll
      for (int ks = 0; ks < 2; ks++) {
#pragma unroll
        for (int dt = 0; dt < 4; dt++) {
          int d   = dt * 32 + l31;
          int row = d >> 1;
          int ch  = (d & 1) * 4 + (2 * ks + gg);   // m>>3 = 2ks+gg
          bf16x8 vb = *(const bf16x8*)((char*)Vtb + row * 128 + ((ch ^ (row & 7)) << 4));
          Of[dt] = __builtin_amdgcn_mfma_f32_32x32x16_bf16(pa[ks], vb, Of[dt], 0, 0, 0);
        }
      }
      __builtin_amdgcn_s_setprio(0);
    }

    __builtin_amdgcn_sched_barrier(0);
    __builtin_amdgcn_s_barrier();   // frees Vtb and Kf[cur] for next tile's writes
    cur ^= 1;
  }

  // ---- epilogue: coalesced 4B stores for rows n < len ----
#pragma unroll
  for (int dt = 0; dt < 4; dt++) {
    int d = dt * 32 + l31;
#pragma unroll
    for (int r = 0; r < 16; r++) {
      int nloc = 4 * gg + (r & 3) + 8 * (r >> 2);
      int n = nb + nloc;
      if (n < len)
        out[(size_t)(off + n) * (HEADS * DQ) + h * DQ + d] = Of[dt][r];
    }
  }
}

extern "C" void kernel_launch(void* const* d_in, const int* in_sizes, int n_in,
                              void* d_out, int out_size, void* d_ws, size_t ws_size,
                              hipStream_t stream) {
  const float* qkv         = (const float*)d_in[0];
  const int*   seq_offsets = (const int*)d_in[1];
  float*       out         = (float*)d_out;
  int Z = in_sizes[1] - 1;
  dim3 grid(NQT * Z, HEADS);
  hstu_attn_kernel<<<grid, dim3(256), 0, stream>>>(qkv, seq_offsets, out, Z);
}

// Round 8
// 96.802 us; speedup vs baseline: 1.4922x; 1.4922x over previous
//
#include <hip/hip_runtime.h>
#include <hip/hip_bf16.h>

namespace {

constexpr int HEADS = 4;
constexpr int DQ    = 128;
constexpr int KVB   = 64;
constexpr int QB    = 128;
constexpr int NQT   = 3;               // max len 383 -> 3 q-tiles of 128
constexpr int ROWF  = 3 * DQ * HEADS;  // 1536 floats per token row
constexpr float ALPHA = 0.08838834764831843f;
constexpr float INV_N = 1.0f / 512.0f;

typedef __bf16 bf16x8 __attribute__((ext_vector_type(8)));
typedef float  f32x16 __attribute__((ext_vector_type(16)));
typedef float  f32x4  __attribute__((ext_vector_type(4)));
typedef unsigned int u32;
typedef u32 u32x4 __attribute__((ext_vector_type(4)));

union FragU { u32x4 u; bf16x8 v; };

__device__ __forceinline__ u32 pkbf(float lo, float hi) {
  u32 r;
  asm("v_cvt_pk_bf16_f32 %0, %1, %2" : "=v"(r) : "v"(lo), "v"(hi));
  return r;
}

__device__ __forceinline__ float silu_p(float acc) {
  float s = acc * ALPHA;
  return s * INV_N * __builtin_amdgcn_rcpf(1.0f + __expf(-s));
}

} // namespace

// Block = (qt, b, h): 4 waves, wave w owns q-rows qt*128 + 32w .. +31.
// K and V both reg-staged (pinned loads survive across barriers) and packed
// to bf16 in single-buffered LDS: Kb [m][d] 16KB + Vtb (V^T) 16KB = 32KB.
// P redistribution via v_permlane32_swap_b32 (no LDS, no bpermute).
__global__ __launch_bounds__(256, 2)
void hstu_attn_kernel(const float* __restrict__ qkv,
                      const int* __restrict__ seq_offsets,
                      float* __restrict__ out,
                      int Z)
{
  const int xi = blockIdx.x;
  const int qt = (NQT - 1) - xi / Z;          // heavy q-tiles first
  const int b  = (Z - 1) - (xi % Z);          // long sequences first
  const int h  = blockIdx.y;
  const int off = seq_offsets[b];
  const int len = seq_offsets[b + 1] - off;
  if (qt * QB >= len) return;

  __shared__ __align__(16) unsigned short Kb[KVB * DQ];   // 16 KB bf16 [m][d]
  __shared__ __align__(16) unsigned short Vtb[KVB * DQ];  // 16 KB bf16 V^T

  const int t   = threadIdx.x;
  const int l   = t & 63;
  const int l31 = l & 31;
  const int gg  = l >> 5;
  const int nb  = qt * QB + 32 * (t >> 6);   // wave's first q row

  const float* __restrict__ base = qkv + (size_t)off * ROWF + h * (3 * DQ);

  // ---- K staging: thread owns row kr = t>>2, d-range kd0..kd0+31 ----
  const int kr  = t >> 2;
  const int kq  = t & 3;
  const int kd0 = kq * 32;
  f32x4 kraw[8];

  auto issue_k = [&](int m0) {
    int rm = m0 + kr; rm = rm < len ? rm : len - 1;
    const f32x4* kp = (const f32x4*)(base + (size_t)rm * ROWF + DQ + kd0);
#pragma unroll
    for (int i = 0; i < 8; i++) kraw[i] = kp[i];
#pragma unroll
    for (int i = 0; i < 8; i++) asm volatile("" :: "v"(kraw[i]));  // pin
  };

  // pack K -> bf16 LDS row kr (256B = 16 chunks of 16B), chunk c = d/8,
  // slot = c ^ (kr & 15)
  auto pack_k = [&]() {
    char* krow = (char*)Kb + kr * 256;
#pragma unroll
    for (int i = 0; i < 4; i++) {
      u32x4 wv;
      wv[0] = pkbf(kraw[2 * i][0], kraw[2 * i][1]);
      wv[1] = pkbf(kraw[2 * i][2], kraw[2 * i][3]);
      wv[2] = pkbf(kraw[2 * i + 1][0], kraw[2 * i + 1][1]);
      wv[3] = pkbf(kraw[2 * i + 1][2], kraw[2 * i + 1][3]);
      int c = 4 * kq + i;
      *(u32x4*)(krow + ((c ^ (kr & 15)) << 4)) = wv;
    }
  };

  // ---- V staging: thread owns rows (m0p, m0p+1), d-range d0v..d0v+15 ----
  const int m0p = (t >> 3) * 2;
  const int d0v = (t & 7) * 16;
  f32x4 vraw[8];

  auto issue_v = [&](int m0) {
    int r0 = m0 + m0p;     r0 = r0 < len ? r0 : len - 1;
    int r1 = m0 + m0p + 1; r1 = r1 < len ? r1 : len - 1;
    const f32x4* p0 = (const f32x4*)(base + (size_t)r0 * ROWF + 2 * DQ + d0v);
    const f32x4* p1 = (const f32x4*)(base + (size_t)r1 * ROWF + 2 * DQ + d0v);
#pragma unroll
    for (int i = 0; i < 4; i++) { vraw[i] = p0[i]; vraw[4 + i] = p1[i]; }
#pragma unroll
    for (int i = 0; i < 8; i++) asm volatile("" :: "v"(vraw[i]));  // pin
  };

  auto pack_v = [&]() {
#pragma unroll
    for (int jj = 0; jj < 16; jj++) {
      int d   = d0v + jj;
      int row = d >> 1;
      int ch  = (d & 1) * 8 + (m0p >> 3);
      u32 pv  = pkbf(vraw[jj >> 2][jj & 3], vraw[4 + (jj >> 2)][jj & 3]);
      *(u32*)((char*)Vtb + row * 256 + ((ch ^ (row & 15)) << 4) + (m0p & 7) * 2) = pv;
    }
  };

  issue_k(0);
  issue_v(0);

  // ---- Q fragments (B-operand of swapped QK^T): lane holds Q[n=l31][d=16ks+8gg+j] ----
  bf16x8 qf[8];
  {
    int n  = nb + l31;
    int rq = n < len ? n : len - 1;   // clamped rows never stored
    const float* qrow = base + (size_t)rq * ROWF;
#pragma unroll
    for (int ks = 0; ks < 8; ks++) {
      int d = ks * 16 + gg * 8;
      f32x4 a0 = *(const f32x4*)(qrow + d);
      f32x4 a1 = *(const f32x4*)(qrow + d + 4);
      FragU u;
      u.u[0] = pkbf(a0[0], a0[1]);
      u.u[1] = pkbf(a0[2], a0[3]);
      u.u[2] = pkbf(a1[0], a1[1]);
      u.u[3] = pkbf(a1[2], a1[3]);
      qf[ks] = u.v;
    }
  }

  f32x16 Of[4];
#pragma unroll
  for (int i = 0; i < 4; i++)
#pragma unroll
    for (int r = 0; r < 16; r++) Of[i][r] = 0.0f;

  const int nkv = min((len + KVB - 1) >> 6, 2 * qt + 2);

  for (int kvt = 0; kvt < nkv; kvt++) {
    const int m0 = kvt * KVB;

    pack_k();   // waits kraw (vmcnt), overlaps vraw tail
    pack_v();   // waits vraw
    if (kvt + 1 < nkv) {
      issue_k(m0 + KVB);   // next-tile loads stay in flight across barrier
      issue_v(m0 + KVB);
    }
    asm volatile("s_waitcnt lgkmcnt(0)" ::: "memory");
    __builtin_amdgcn_s_barrier();
    __builtin_amdgcn_sched_barrier(0);

    if (nb < len && m0 <= nb + 31) {   // wave-uniform causal skip
      const bool needmask = (m0 + KVB - 1) > nb;
      bf16x8 pa[4];

#pragma unroll
      for (int mt = 0; mt < 2; mt++) {
        f32x16 acc;
#pragma unroll
        for (int r = 0; r < 16; r++) acc[r] = 0.0f;
        const int mrow = mt * 32 + l31;
        const char* krow = (const char*)Kb + mrow * 256;
        const int   ksw  = mrow & 15;
        __builtin_amdgcn_s_setprio(1);
#pragma unroll
        for (int ks = 0; ks < 8; ks++) {
          int cb = 2 * ks + gg;   // chunk = d/8, d = 16ks+8gg
          bf16x8 kb = *(const bf16x8*)(krow + ((cb ^ ksw) << 4));
          // S^T = K * Q^T : lane holds n=l31, m=(r&3)+8(r>>2)+4gg+32mt
          acc = __builtin_amdgcn_mfma_f32_32x32x16_bf16(kb, qf[ks], acc, 0, 0, 0);
        }
        __builtin_amdgcn_s_setprio(0);

        // silu + causal mask, pack bf16 pairs (m, m+1)
        u32 wk[8];
#pragma unroll
        for (int i = 0; i < 8; i++) {
          int r  = 2 * i;
          int mr = m0 + (r & 3) + 8 * (r >> 2) + 4 * gg + 32 * mt;
          float p0 = silu_p(acc[r]);
          float p1 = silu_p(acc[r + 1]);
          if (needmask) {
            int nglob = nb + l31;
            if (mr > nglob)     p0 = 0.0f;
            if (mr + 1 > nglob) p1 = 0.0f;
          }
          wk[i] = pkbf(p0, p1);
        }

        // redistribute halves lane<->lane+32 via permlane32_swap:
        // swap(a,b): a' = {a.lo, b.lo-shifted}, b' = {a.hi-shifted, b.hi}
        FragU fa, fb;
        fa.u[0] = wk[0]; fa.u[1] = wk[1]; fa.u[2] = wk[2]; fa.u[3] = wk[3];
        fb.u[0] = wk[4]; fb.u[1] = wk[5]; fb.u[2] = wk[6]; fb.u[3] = wk[7];
        asm("v_permlane32_swap_b32 %0, %1" : "+v"(fa.u[0]), "+v"(fa.u[2]));
        asm("v_permlane32_swap_b32 %0, %1" : "+v"(fa.u[1]), "+v"(fa.u[3]));
        asm("v_permlane32_swap_b32 %0, %1" : "+v"(fb.u[0]), "+v"(fb.u[2]));
        asm("v_permlane32_swap_b32 %0, %1" : "+v"(fb.u[1]), "+v"(fb.u[3]));
        pa[2 * mt]     = fa.v;
        pa[2 * mt + 1] = fb.v;
      }

      // ---- PV: O += P * V^T (A = P frags in reg, B = V^T from LDS) ----
      __builtin_amdgcn_s_setprio(1);
#pragma unroll
      for (int ks = 0; ks < 4; ks++) {
#pragma unroll
        for (int dt = 0; dt < 4; dt++) {
          int d   = dt * 32 + l31;
          int row = d >> 1;
          int ch  = (d & 1) * 8 + (2 * ks + gg);   // m>>3 = 2ks+gg
          bf16x8 vb = *(const bf16x8*)((char*)Vtb + row * 256 + ((ch ^ (row & 15)) << 4));
          Of[dt] = __builtin_amdgcn_mfma_f32_32x32x16_bf16(pa[ks], vb, Of[dt], 0, 0, 0);
        }
      }
      __builtin_amdgcn_s_setprio(0);
    }

    __builtin_amdgcn_sched_barrier(0);
    __builtin_amdgcn_s_barrier();   // frees Kb/Vtb for next tile's writes
  }

  // ---- epilogue: coalesced 4B stores for rows n < len ----
#pragma unroll
  for (int dt = 0; dt < 4; dt++) {
    int d = dt * 32 + l31;
#pragma unroll
    for (int r = 0; r < 16; r++) {
      int nloc = 4 * gg + (r & 3) + 8 * (r >> 2);
      int n = nb + nloc;
      if (n < len)
        out[(size_t)(off + n) * (HEADS * DQ) + h * DQ + d] = Of[dt][r];
    }
  }
}

extern "C" void kernel_launch(void* const* d_in, const int* in_sizes, int n_in,
                              void* d_out, int out_size, void* d_ws, size_t ws_size,
                              hipStream_t stream) {
  const float* qkv         = (const float*)d_in[0];
  const int*   seq_offsets = (const int*)d_in[1];
  float*       out         = (float*)d_out;
  int Z = in_sizes[1] - 1;
  dim3 grid(NQT * Z, HEADS);
  hstu_attn_kernel<<<grid, dim3(256), 0, stream>>>(qkv, seq_offsets, out, Z);
}

// Round 9
// 87.076 us; speedup vs baseline: 1.6589x; 1.1117x over previous
//
#include <hip/hip_runtime.h>
#include <hip/hip_bf16.h>

namespace {

constexpr int HEADS = 4;
constexpr int DQ    = 128;
constexpr int KVB   = 64;
constexpr int QB    = 128;
constexpr int NQT   = 3;               // max len 383 -> 3 q-tiles of 128
constexpr int ROWF  = 3 * DQ * HEADS;  // 1536 floats per token row
constexpr float ALPHA = 0.08838834764831843f;
constexpr float INV_N = 1.0f / 512.0f;

typedef __bf16 bf16x8 __attribute__((ext_vector_type(8)));
typedef float  f32x16 __attribute__((ext_vector_type(16)));
typedef float  f32x4  __attribute__((ext_vector_type(4)));
typedef unsigned int u32;
typedef u32 u32x4 __attribute__((ext_vector_type(4)));

union FragU { u32x4 u; bf16x8 v; };

__device__ __forceinline__ u32 pkbf(float lo, float hi) {
  u32 r;
  asm("v_cvt_pk_bf16_f32 %0, %1, %2" : "=v"(r) : "v"(lo), "v"(hi));
  return r;
}

__device__ __forceinline__ float silu_p(float acc) {
  float s = acc * ALPHA;
  return s * INV_N * __builtin_amdgcn_rcpf(1.0f + __expf(-s));
}

} // namespace

// Block = (qt, b, h): 4 waves, wave w owns q-rows qt*128 + 32w .. +31.
// K,V reg-staged (pinned) -> bf16 DOUBLE-buffered LDS (Kb/Vtb x2 = 64KB).
// One barrier per tile: compute(t-1) from buf A overlaps pack(t) into buf B.
__global__ __launch_bounds__(256, 2)
void hstu_attn_kernel(const float* __restrict__ qkv,
                      const int* __restrict__ seq_offsets,
                      float* __restrict__ out,
                      int Z)
{
  const int xi = blockIdx.x;
  const int qt = (NQT - 1) - xi / Z;          // heavy q-tiles first
  const int b  = (Z - 1) - (xi % Z);          // long sequences first
  const int h  = blockIdx.y;
  const int off = seq_offsets[b];
  const int len = seq_offsets[b + 1] - off;
  if (qt * QB >= len) return;

  __shared__ __align__(16) unsigned short Kb[2][KVB * DQ];   // 2 x 16 KB bf16 [m][d]
  __shared__ __align__(16) unsigned short Vtb[2][KVB * DQ];  // 2 x 16 KB bf16 V^T

  const int t   = threadIdx.x;
  const int l   = t & 63;
  const int l31 = l & 31;
  const int gg  = l >> 5;
  const int nb  = qt * QB + 32 * (t >> 6);   // wave's first q row

  const float* __restrict__ base = qkv + (size_t)off * ROWF + h * (3 * DQ);

  // ---- K staging: thread owns row kr = t>>2, chunks {kq+4i} (8 floats each) ----
  // lanes kq=0..3 cover contiguous 32B runs -> coalesced 128B per quad
  const int kr  = t >> 2;
  const int kq  = t & 3;
  f32x4 kraw[8];

  auto issue_k = [&](int m0) {
    int rm = m0 + kr; rm = rm < len ? rm : len - 1;
    const float* kp = base + (size_t)rm * ROWF + DQ;
#pragma unroll
    for (int i = 0; i < 4; i++) {
      const f32x4* p = (const f32x4*)(kp + (kq + 4 * i) * 8);
      kraw[2 * i]     = p[0];
      kraw[2 * i + 1] = p[1];
    }
#pragma unroll
    for (int i = 0; i < 8; i++) asm volatile("" :: "v"(kraw[i]));  // pin
  };

  auto pack_k = [&](int buf) {
    char* krow = (char*)(Kb[buf]) + kr * 256;
#pragma unroll
    for (int i = 0; i < 4; i++) {
      u32x4 wv;
      wv[0] = pkbf(kraw[2 * i][0], kraw[2 * i][1]);
      wv[1] = pkbf(kraw[2 * i][2], kraw[2 * i][3]);
      wv[2] = pkbf(kraw[2 * i + 1][0], kraw[2 * i + 1][1]);
      wv[3] = pkbf(kraw[2 * i + 1][2], kraw[2 * i + 1][3]);
      int c = kq + 4 * i;
      *(u32x4*)(krow + ((c ^ (kr & 15)) << 4)) = wv;
    }
  };

  // ---- V staging: thread owns rows (m0p, m0p+1), d-range d0v..d0v+15 ----
  const int m0p = (t >> 3) * 2;
  const int d0v = (t & 7) * 16;
  f32x4 vraw[8];

  auto issue_v = [&](int m0) {
    int r0 = m0 + m0p;     r0 = r0 < len ? r0 : len - 1;
    int r1 = m0 + m0p + 1; r1 = r1 < len ? r1 : len - 1;
    const f32x4* p0 = (const f32x4*)(base + (size_t)r0 * ROWF + 2 * DQ + d0v);
    const f32x4* p1 = (const f32x4*)(base + (size_t)r1 * ROWF + 2 * DQ + d0v);
#pragma unroll
    for (int i = 0; i < 4; i++) { vraw[i] = p0[i]; vraw[4 + i] = p1[i]; }
#pragma unroll
    for (int i = 0; i < 8; i++) asm volatile("" :: "v"(vraw[i]));  // pin
  };

  auto pack_v = [&](int buf) {
#pragma unroll
    for (int jj = 0; jj < 16; jj++) {
      int d   = d0v + jj;
      int row = d >> 1;
      int ch  = (d & 1) * 8 + (m0p >> 3);
      u32 pv  = pkbf(vraw[jj >> 2][jj & 3], vraw[4 + (jj >> 2)][jj & 3]);
      *(u32*)((char*)(Vtb[buf]) + row * 256 + ((ch ^ (row & 15)) << 4) + (m0p & 7) * 2) = pv;
    }
  };

  issue_k(0);
  issue_v(0);

  // ---- Q fragments (B-operand of swapped QK^T): lane holds Q[n=l31][d=16ks+8gg+j] ----
  bf16x8 qf[8];
  {
    int n  = nb + l31;
    int rq = n < len ? n : len - 1;   // clamped rows never stored
    const float* qrow = base + (size_t)rq * ROWF;
#pragma unroll
    for (int ks = 0; ks < 8; ks++) {
      int d = ks * 16 + gg * 8;
      f32x4 a0 = *(const f32x4*)(qrow + d);
      f32x4 a1 = *(const f32x4*)(qrow + d + 4);
      FragU u;
      u.u[0] = pkbf(a0[0], a0[1]);
      u.u[1] = pkbf(a0[2], a0[3]);
      u.u[2] = pkbf(a1[0], a1[1]);
      u.u[3] = pkbf(a1[2], a1[3]);
      qf[ks] = u.v;
    }
  }

  f32x16 Of[4];
#pragma unroll
  for (int i = 0; i < 4; i++)
#pragma unroll
    for (int r = 0; r < 16; r++) Of[i][r] = 0.0f;

  // ---- per-tile compute: QK^T -> silu -> permlane swap -> PV ----
  auto compute = [&](int kvt) {
    const int m0  = kvt * KVB;
    const int buf = kvt & 1;
    if (nb < len && m0 <= nb + 31) {   // wave-uniform causal skip
      const bool needmask = (m0 + KVB - 1) > nb;
      bf16x8 pa[4];

#pragma unroll
      for (int mt = 0; mt < 2; mt++) {
        f32x16 acc;
#pragma unroll
        for (int r = 0; r < 16; r++) acc[r] = 0.0f;
        const int mrow = mt * 32 + l31;
        const char* krow = (const char*)(Kb[buf]) + mrow * 256;
        const int   ksw  = mrow & 15;
        __builtin_amdgcn_s_setprio(1);
#pragma unroll
        for (int ks = 0; ks < 8; ks++) {
          int cb = 2 * ks + gg;   // chunk = d/8, d = 16ks+8gg
          bf16x8 kb = *(const bf16x8*)(krow + ((cb ^ ksw) << 4));
          // S^T = K * Q^T : lane holds n=l31, m=(r&3)+8(r>>2)+4gg+32mt
          acc = __builtin_amdgcn_mfma_f32_32x32x16_bf16(kb, qf[ks], acc, 0, 0, 0);
        }
        __builtin_amdgcn_s_setprio(0);

        // silu + causal mask, pack bf16 pairs (m, m+1)
        u32 wk[8];
#pragma unroll
        for (int i = 0; i < 8; i++) {
          int r  = 2 * i;
          int mr = m0 + (r & 3) + 8 * (r >> 2) + 4 * gg + 32 * mt;
          float p0 = silu_p(acc[r]);
          float p1 = silu_p(acc[r + 1]);
          if (needmask) {
            int nglob = nb + l31;
            if (mr > nglob)     p0 = 0.0f;
            if (mr + 1 > nglob) p1 = 0.0f;
          }
          wk[i] = pkbf(p0, p1);
        }

        // redistribute halves lane<->lane+32 via permlane32_swap
        FragU fa, fb;
        fa.u[0] = wk[0]; fa.u[1] = wk[1]; fa.u[2] = wk[2]; fa.u[3] = wk[3];
        fb.u[0] = wk[4]; fb.u[1] = wk[5]; fb.u[2] = wk[6]; fb.u[3] = wk[7];
        asm("v_permlane32_swap_b32 %0, %1" : "+v"(fa.u[0]), "+v"(fa.u[2]));
        asm("v_permlane32_swap_b32 %0, %1" : "+v"(fa.u[1]), "+v"(fa.u[3]));
        asm("v_permlane32_swap_b32 %0, %1" : "+v"(fb.u[0]), "+v"(fb.u[2]));
        asm("v_permlane32_swap_b32 %0, %1" : "+v"(fb.u[1]), "+v"(fb.u[3]));
        pa[2 * mt]     = fa.v;
        pa[2 * mt + 1] = fb.v;
      }

      // PV: O += P * V^T (A = P frags in reg, B = V^T from LDS)
      __builtin_amdgcn_s_setprio(1);
#pragma unroll
      for (int ks = 0; ks < 4; ks++) {
#pragma unroll
        for (int dt = 0; dt < 4; dt++) {
          int d   = dt * 32 + l31;
          int row = d >> 1;
          int ch  = (d & 1) * 8 + (2 * ks + gg);   // m>>3 = 2ks+gg
          bf16x8 vb = *(const bf16x8*)((char*)(Vtb[buf]) + row * 256 + ((ch ^ (row & 15)) << 4));
          Of[dt] = __builtin_amdgcn_mfma_f32_32x32x16_bf16(pa[ks], vb, Of[dt], 0, 0, 0);
        }
      }
      __builtin_amdgcn_s_setprio(0);
    }
  };

  const int nkv = min((len + KVB - 1) >> 6, 2 * qt + 2);

  for (int kvt = 0; kvt < nkv; kvt++) {
    // compute previous tile (other buffer) BEFORE this tile's pack drain:
    // MFMAs issue first in-wave; pack's vmcnt wait overlaps other waves' MFMAs.
    if (kvt > 0) compute(kvt - 1);

    pack_k(kvt & 1);                 // waits kraw (vmcnt), writes buf[kvt&1]
    pack_v(kvt & 1);                 // waits vraw
    if (kvt + 1 < nkv) {
      issue_k((kvt + 1) * KVB);      // next-tile loads fly across the barrier
      issue_v((kvt + 1) * KVB);
    }
    asm volatile("s_waitcnt lgkmcnt(0)" ::: "memory");
    __builtin_amdgcn_s_barrier();    // single barrier per tile
    __builtin_amdgcn_sched_barrier(0);
  }
  compute(nkv - 1);                  // tail

  // ---- epilogue: coalesced 4B stores for rows n < len ----
#pragma unroll
  for (int dt = 0; dt < 4; dt++) {
    int d = dt * 32 + l31;
#pragma unroll
    for (int r = 0; r < 16; r++) {
      int nloc = 4 * gg + (r & 3) + 8 * (r >> 2);
      int n = nb + nloc;
      if (n < len)
        out[(size_t)(off + n) * (HEADS * DQ) + h * DQ + d] = Of[dt][r];
    }
  }
}

extern "C" void kernel_launch(void* const* d_in, const int* in_sizes, int n_in,
                              void* d_out, int out_size, void* d_ws, size_t ws_size,
                              hipStream_t stream) {
  const float* qkv         = (const float*)d_in[0];
  const int*   seq_offsets = (const int*)d_in[1];
  float*       out         = (float*)d_out;
  int Z = in_sizes[1] - 1;
  dim3 grid(NQT * Z, HEADS);
  hstu_attn_kernel<<<grid, dim3(256), 0, stream>>>(qkv, seq_offsets, out, Z);
}